// Round 11
// baseline (187.910 us; speedup 1.0000x reference)
//
#include <hip/hip_runtime.h>
#include <hip/hip_bf16.h>

// ConceptGaussians: out_means[b,d] = mean[d, labels[b,d]],
//                   out_logvars[b,d] = log_var[d, labels[b,d]]
// B = 2097152, N_DOMAINS = 8, MAX_CONCEPTS = 64.
//
// FINAL model (R0-R10 ledger, all rounds consistent, zero contradictions):
//   - labels : INT32 [B,8] flat C-order, 67 MB (harness converts int64 per
//              "integer -> const int*"; R3 crash = reads past 67 MB)
//   - tables : FLOAT32 [8,64] C-order (R1: ushort reads -> NaN)
//   - out    : *** FLOAT32 ***, 33.5M floats = [means B*8 | logvars B*8],
//              C-order ("reference's OUTPUT dtype ... else float*").
//     The R1-R10 mystery: I wrote bf16 ushort pairs into the fp32 buffer;
//     each fp32 readback ~= the bf16 value in its HIGH half => scrambled
//     +-10 values => the layout-invariant exact-20.0 across six rounds,
//     and R1's NaN (random exponent from packed pairs). Output dtype, not
//     input layout, was the broken axis.
//
// Memory-bound gather: 67 MB label read + 134 MB fp32 write = 201 MB.

constexpr int N_DOMAINS    = 8;
constexpr int MAX_CONCEPTS = 64;
constexpr int TABLE_SIZE   = N_DOMAINS * MAX_CONCEPTS;  // 512
constexpr int BLOCK        = 256;

// int32-coded labels are 0..63 (bit pattern < 64); fp32-coded labels >= 1.0
// have bit patterns >= 0x3F800000; 0.0 takes the int path correctly.
// Exact under both codings; &63 guards the LDS index regardless.
static __device__ inline int decode_label(int w) {
    int v = ((unsigned)w < 64u) ? w : (int)__int_as_float(w);
    return v & 63;
}

__global__ __launch_bounds__(BLOCK) void concept_gather_kernel(
    const int* __restrict__ labels,        // [B, 8] int32, flat C
    const float* __restrict__ mean,        // [8, 64] fp32, C
    const float* __restrict__ log_var,     // [8, 64] fp32, C
    float* __restrict__ out,               // fp32: [B*8 means][B*8 logvars], C
    int batch,
    int half_elems)
{
    __shared__ float2 table[TABLE_SIZE];   // [d][c] = {mean, log_var}, 4 KB

    const int t = threadIdx.x;

    // Stage paired table: one ds_read_b64 later serves both outputs.
    for (int i = t; i < TABLE_SIZE; i += BLOCK) {
        table[i] = make_float2(mean[i], log_var[i]);
    }
    __syncthreads();

    const int b = blockIdx.x * BLOCK + t;
    if (b >= batch) return;

    // 8 labels: two coalesced 16B loads.
    const int4* lab4 = (const int4*)labels;
    const int4 l0 = lab4[2 * b];
    const int4 l1 = lab4[2 * b + 1];

    const float2 e0 = table[0 * MAX_CONCEPTS + decode_label(l0.x)];
    const float2 e1 = table[1 * MAX_CONCEPTS + decode_label(l0.y)];
    const float2 e2 = table[2 * MAX_CONCEPTS + decode_label(l0.z)];
    const float2 e3 = table[3 * MAX_CONCEPTS + decode_label(l0.w)];
    const float2 e4 = table[4 * MAX_CONCEPTS + decode_label(l1.x)];
    const float2 e5 = table[5 * MAX_CONCEPTS + decode_label(l1.y)];
    const float2 e6 = table[6 * MAX_CONCEPTS + decode_label(l1.z)];
    const float2 e7 = table[7 * MAX_CONCEPTS + decode_label(l1.w)];

    // Means: floats out[b*8 .. b*8+7]  -> two float4 stores at float4-index 2b.
    // Logvars: same at out + half_elems. All fully coalesced.
    float4* mo = (float4*)out;
    float4* vo = (float4*)(out + half_elems);
    mo[2 * b + 0] = make_float4(e0.x, e1.x, e2.x, e3.x);
    mo[2 * b + 1] = make_float4(e4.x, e5.x, e6.x, e7.x);
    vo[2 * b + 0] = make_float4(e0.y, e1.y, e2.y, e3.y);
    vo[2 * b + 1] = make_float4(e4.y, e5.y, e6.y, e7.y);
}

extern "C" void kernel_launch(void* const* d_in, const int* in_sizes, int n_in,
                              void* d_out, int out_size, void* d_ws, size_t ws_size,
                              hipStream_t stream) {
    const int* labels      = (const int*)d_in[0];
    const float* mean      = (const float*)d_in[1];
    const float* log_var   = (const float*)d_in[2];
    float* out             = (float*)d_out;

    const int batch      = out_size / (2 * N_DOMAINS);   // 2097152
    const int half_elems = out_size / 2;                 // 16777216
    const int blocks     = (batch + BLOCK - 1) / BLOCK;

    concept_gather_kernel<<<blocks, BLOCK, 0, stream>>>(
        labels, mean, log_var, out, batch, half_elems);
}

// Round 13
// 184.173 us; speedup vs baseline: 1.0203x; 1.0203x over previous
//
#include <hip/hip_runtime.h>
#include <hip/hip_bf16.h>

// ConceptGaussians: out_means[b,d] = mean[d, labels[b,d]],
//                   out_logvars[b,d] = log_var[d, labels[b,d]]
// B = 2097152, N_DOMAINS = 8, MAX_CONCEPTS = 64.
// Model (verified PASS in R11, absmax 0.0):
//   labels int32 [B,8] C / tables fp32 [8,64] C / out fp32 [means|logvars] C.
//
// R13 = R12 with the compile fix: __builtin_nontemporal_store needs a native
// vector type, not HIP_vector_type — use ext_vector_type(4) float.
// Mapping: thread gid handles sample gid>>1, domains 4*(gid&1)..+3; every
// global access lane-consecutive 16B (perfect coalescing). Nontemporal
// stores keep the 134MB write stream out of L2.
// Traffic: 67MB in + 134MB out -> ~32us roofline at 6.3 TB/s.

constexpr int N_DOMAINS    = 8;
constexpr int MAX_CONCEPTS = 64;
constexpr int TABLE_SIZE   = N_DOMAINS * MAX_CONCEPTS;  // 512
constexpr int BLOCK        = 256;

typedef float v4f __attribute__((ext_vector_type(4)));  // native vec for NT store

// int32-coded labels are 0..63 (bit pattern < 64); fp32-coded labels >= 1.0
// have bit patterns >= 0x3F800000; 0.0 takes the int path. &63 guards LDS.
static __device__ inline int decode_label(int w) {
    int v = ((unsigned)w < 64u) ? w : (int)__int_as_float(w);
    return v & 63;
}

__global__ __launch_bounds__(BLOCK) void concept_gather_kernel(
    const int4* __restrict__ lab4,         // [2B] int4 = label quads, flat C
    const float* __restrict__ mean,        // [8, 64] fp32, C
    const float* __restrict__ log_var,     // [8, 64] fp32, C
    v4f* __restrict__ means4,              // [2B] float4 at out[0..]
    v4f* __restrict__ logvars4,            // [2B] float4 at out[half..]
    int nquads)                            // 2 * batch
{
    __shared__ float2 table[TABLE_SIZE];   // [d][c] = {mean, log_var}, 4 KB

    const int t = threadIdx.x;
    for (int i = t; i < TABLE_SIZE; i += BLOCK) {
        table[i] = make_float2(mean[i], log_var[i]);
    }
    __syncthreads();

    const int gid = blockIdx.x * BLOCK + t;
    if (gid >= nquads) return;

    // One lane-consecutive 16B label load: 4 labels = half a sample.
    const int4 l = lab4[gid];

    // Domain base: even gid -> domains 0..3, odd gid -> domains 4..7.
    const int dbase = (gid & 1) * 4 * MAX_CONCEPTS;

    const float2 e0 = table[dbase + 0 * MAX_CONCEPTS + decode_label(l.x)];
    const float2 e1 = table[dbase + 1 * MAX_CONCEPTS + decode_label(l.y)];
    const float2 e2 = table[dbase + 2 * MAX_CONCEPTS + decode_label(l.z)];
    const float2 e3 = table[dbase + 3 * MAX_CONCEPTS + decode_label(l.w)];

    // Lane-consecutive 16B stores; nontemporal (write-only 134MB stream).
    v4f mo = { e0.x, e1.x, e2.x, e3.x };
    v4f vo = { e0.y, e1.y, e2.y, e3.y };
    __builtin_nontemporal_store(mo, &means4[gid]);
    __builtin_nontemporal_store(vo, &logvars4[gid]);
}

extern "C" void kernel_launch(void* const* d_in, const int* in_sizes, int n_in,
                              void* d_out, int out_size, void* d_ws, size_t ws_size,
                              hipStream_t stream) {
    const int4* lab4       = (const int4*)d_in[0];
    const float* mean      = (const float*)d_in[1];
    const float* log_var   = (const float*)d_in[2];
    float* out             = (float*)d_out;

    const int batch      = out_size / (2 * N_DOMAINS);   // 2097152
    const int half_elems = out_size / 2;                 // 16777216
    const int nquads     = 2 * batch;                    // 4194304
    const int blocks     = (nquads + BLOCK - 1) / BLOCK; // 16384

    concept_gather_kernel<<<blocks, BLOCK, 0, stream>>>(
        lab4, mean, log_var,
        (v4f*)out, (v4f*)(out + half_elems), nquads);
}